// Round 1
// baseline (515.159 us; speedup 1.0000x reference)
//
#include <hip/hip_runtime.h>

typedef unsigned int u32;
typedef unsigned long long u64;

#define BB 2
#define TT 4
#define NF 8            // B*T frames
#define RR 128          // rois
#define NSAMP 32        // num_sample
#define KK2 5           // max points per fine voxel
#define MAXV 50000
#define GX1 376
#define GY1 376
#define C1 141376       // GX1*GY1 (gz=1)
#define NC1 1131008     // NF*C1
#define GX2 752
#define GY2 752
#define GZ2 30
#define BIG2 16965120u  // GX2*GY2*GZ2
#define NPAD 262144     // 2^18 >= max kept points (<= N = 240000)
#define NMAXP 262144
#define MAXROWS 1536

#define PCX (-75.2f)
#define PCY (-75.2f)
#define PCZ (-2.0f)
#define VS1 0.4f
#define VSH 0.2f
#define VZ1 6.0f

// ---------------- box params ----------------
// layout per (f,r), 12 u32 words:
// 0:bx 1:by 2:cur_r^2 3:zmax (floats); 4:Qx 5:Qy 6:irad 7:Q1x 8:Q1y 9:irad2 (ints)
__global__ void k_rois(const float* traj, const float* back, const unsigned char* vlb, u32* boxp)
{
    int tid = blockIdx.x * blockDim.x + threadIdx.x;
    if (tid >= NF * RR) return;
    // detect valid_length storage: int32 (0/1 -> bytes at %4!=0 are 0) vs uint8/bool
    bool isU8 = false;
    for (int k = 1; k < 64; k++)
        if ((k & 3) && vlb[k]) isU8 = true;
    bool vl = isU8 ? (vlb[tid] != 0) : (((const int*)vlb)[tid] != 0);
    const float* tb = traj + tid * 7;
    const float* bb = back + tid * 7;
    float bx = vl ? (tb[0] + bb[0]) * 0.5f : bb[0];
    float by = vl ? (tb[1] + bb[1]) * 0.5f : bb[1];
    float bz = bb[2], dx = bb[3], dy = bb[4], dz = bb[5];
    float hx = dx * 0.5f, hy = dy * 0.5f;
    float r0 = sqrtf(hx * hx + hy * hy);
    float radf = ceilf(r0 * 1.1f / 0.4f);
    float curr = r0 * 1.1f;
    u32* bp = boxp + tid * 12;
    bp[0] = __float_as_uint(bx);
    bp[1] = __float_as_uint(by);
    bp[2] = __float_as_uint(curr * curr);
    bp[3] = __float_as_uint(bz + dz * 0.6f);
    bp[4] = (u32)(int)floorf((bx - PCX) / VS1);
    bp[5] = (u32)(int)floorf((by - PCY) / VS1);
    bp[6] = (u32)(int)radf;
    bp[7] = (u32)(int)floorf((bx - PCX) / VSH);
    bp[8] = (u32)(int)floorf((by - PCY) / VSH);
    bp[9] = (u32)(2 * (int)radf);
}

// ---------------- stage-1 voxelize ----------------
__global__ void k_points(const float* P, int n, u32* pvid, u32* cnt1)
{
    int i = blockIdx.x * blockDim.x + threadIdx.x;
    if (i >= n) return;
    const float* p = P + (size_t)i * 6;
    float bsf = p[0], x = p[1], y = p[2], z = p[3], tt = p[5];
    u32 g = 0xFFFFFFFFu;
    int b = (int)bsf;
    int t = (int)floorf(tt * 10.0f + 0.5f);
    if (bsf == (float)b && b >= 0 && b < BB && t >= 0 && t < TT &&
        fabsf(tt - 0.1f * (float)t) < 0.001f) {
        float fx = floorf((x - PCX) / VS1);
        float fy = floorf((y - PCY) / VS1);
        float fz = floorf((z - PCZ) / VZ1);
        if (fx >= 0.f && fx < (float)GX1 && fy >= 0.f && fy < (float)GY1 && fz == 0.f) {
            g = (u32)((b * TT + t) * C1) + (u32)fy * GX1 + (u32)fx;
        }
    }
    pvid[i] = g;
    if (g != 0xFFFFFFFFu) atomicAdd(&cnt1[g], 1u);
}

// ---------------- generic paired exclusive scan (lo=u32 scan A, hi=u32 scan B) ----------------
// MODE 0: in=counts -> lo:prefix(count) hi:prefix(count!=0)
// MODE 1: in=u32    -> lo:prefix(in)    hi:unused
// MODE 2: heads from sorted keys -> lo:prefix(head) hi:unused
template <int MODE>
__global__ void k_scan_partial(const u32* in, const u64* keys, const u32* mtp,
                               u32* out_lo, u32* out_hi, u64* partials, int n)
{
    __shared__ u64 sh[256];
    int blk = blockIdx.x, t = threadIdx.x;
    int base = blk * 2048 + t * 8;
    u32 Mt = 0;
    if (MODE == 2) Mt = mtp[0];
    u64 pref[8];
    u64 sum = 0;
    for (int e = 0; e < 8; e++) {
        int i = base + e;
        u64 v = 0;
        if (i < n) {
            if (MODE == 0) { u32 c = in[i]; v = (u64)c | ((u64)(c != 0) << 32); }
            else if (MODE == 1) { v = in[i]; }
            else {
                if ((u32)i < Mt) {
                    u64 kc = keys[i];
                    u32 vid = (u32)((kc >> 18) & 0x1FFFFFFu);
                    if (vid != BIG2 && (i == 0 || (keys[i - 1] >> 18) != (kc >> 18))) v = 1;
                }
            }
        }
        pref[e] = sum;
        sum += v;
    }
    sh[t] = sum;
    __syncthreads();
    for (int off = 1; off < 256; off <<= 1) {
        u64 y = (t >= off) ? sh[t - off] : 0;
        __syncthreads();
        sh[t] += y;
        __syncthreads();
    }
    u64 texcl = sh[t] - sum;
    if (t == 255) partials[blk] = sh[255];
    for (int e = 0; e < 8; e++) {
        int i = base + e;
        if (i < n) {
            u64 v = texcl + pref[e];
            out_lo[i] = (u32)v;
            out_hi[i] = (u32)(v >> 32);
        }
    }
}

__global__ void k_scan_level2(u64* partials, int nb, u32* out_lo, u32* out_hi, int n)
{
    if (threadIdx.x == 0 && blockIdx.x == 0) {
        u64 run = 0;
        for (int i = 0; i < nb; i++) { u64 p = partials[i]; partials[i] = run; run += p; }
        out_lo[n] = (u32)run;
        out_hi[n] = (u32)(run >> 32);
    }
}

__global__ void k_scan_addback(u32* out_lo, u32* out_hi, const u64* partials, int n)
{
    int i = blockIdx.x * blockDim.x + threadIdx.x;
    if (i >= n) return;
    u64 b = partials[i >> 11];
    out_lo[i] += (u32)b;
    out_hi[i] += (u32)(b >> 32);
}

// ---------------- stage-1 scatter + per-cell sort + compact ----------------
__global__ void k_scatter(const u32* pvid, int n, const u32* starts, u32* cursor, u32* ptbuf)
{
    int i = blockIdx.x * blockDim.x + threadIdx.x;
    if (i >= n) return;
    u32 g = pvid[i];
    if (g == 0xFFFFFFFFu) return;
    u32 pos = atomicAdd(&cursor[g], 1u);
    ptbuf[starts[g] + pos] = (u32)i;
}

__global__ void k_cellsort(const u32* cnt1, const u32* starts, u32* ptbuf)
{
    int c = blockIdx.x * blockDim.x + threadIdx.x;
    if (c >= NC1) return;
    u32 n = cnt1[c];
    if (n < 2) return;
    u32 s0 = starts[c];
    for (u32 a = 1; a < n; a++) {
        u32 v = ptbuf[s0 + a];
        int bpos = (int)a;
        while (bpos > 0 && ptbuf[s0 + bpos - 1] > v) { ptbuf[s0 + bpos] = ptbuf[s0 + bpos - 1]; bpos--; }
        ptbuf[s0 + bpos] = v;
    }
}

__global__ void k_buildvox(const u32* cnt1, const u32* starts, const u32* flagsc,
                           u32* vcoord, u32* vcount, u32* vstart)
{
    int c = blockIdx.x * blockDim.x + threadIdx.x;
    if (c >= NC1) return;
    u32 n = cnt1[c];
    if (!n) return;
    int f = c / C1;
    int lv = c % C1;
    u32 slot = flagsc[c] - flagsc[f * C1];
    if (slot >= MAXV) return;
    u32 idx = (u32)f * MAXV + slot;
    vcoord[idx] = (u32)(lv % GX1) | ((u32)(lv / GX1) << 16);
    vcount[idx] = n < 32u ? n : 32u;
    vstart[idx] = starts[c];
}

// ---------------- stage-1 roi mask ----------------
__global__ void k_vmask(const u32* flagsc, const u32* vcoord, const u32* vcount,
                        const u32* boxp, u32* npm)
{
    int idx = blockIdx.x * blockDim.x + threadIdx.x;
    if (idx >= NF * MAXV) return;
    int f = idx / MAXV;
    u32 nv1 = flagsc[(f + 1) * C1] - flagsc[f * C1];
    if (nv1 > (u32)MAXV) nv1 = MAXV;
    u32 slot = (u32)(idx % MAXV);
    u32 res = 0;
    if (slot < nv1) {
        u32 cc = vcoord[idx];
        int cx = (int)(cc & 0xFFFFu), cy = (int)(cc >> 16);
        const u32* bp = boxp + f * RR * 12;
        for (int r = 0; r < RR; r++) {
            int Qx = (int)bp[r * 12 + 4], Qy = (int)bp[r * 12 + 5], ir = (int)bp[r * 12 + 6];
            int ax = Qx - cx; if (ax < 0) ax = -ax;
            int ay = Qy - cy; if (ay < 0) ay = -ay;
            if (ax < ir && ay < ir) { res = vcount[idx]; break; }
        }
    }
    npm[idx] = res;
}

// ---------------- emit kept points + stage-2 keys ----------------
__global__ void k_emitkept(const float* P, const u32* npm, const u32* koff, const u32* vstart,
                           const u32* ptbuf, u32* kept, u64* keys)
{
    int idx = blockIdx.x * blockDim.x + threadIdx.x;
    if (idx >= NF * MAXV) return;
    u32 m = npm[idx];
    if (!m) return;
    u32 base = koff[idx];
    u32 vs = vstart[idx];
    u64 fr = (u64)(idx / MAXV);
    for (u32 r = 0; r < m; r++) {
        u32 pidx = ptbuf[vs + r];
        u32 seq = base + r;
        kept[seq] = pidx;
        const float* p = P + (size_t)pidx * 6;
        float fx = floorf((p[1] - PCX) / VSH);
        float fy = floorf((p[2] - PCY) / VSH);
        float fz = floorf((p[3] - PCZ) / VSH);
        u32 vid = BIG2;
        if (fx >= 0.f && fx < (float)GX2 && fy >= 0.f && fy < (float)GY2 &&
            fz >= 0.f && fz < (float)GZ2)
            vid = ((u32)fz * GY2 + (u32)fy) * GX2 + (u32)fx;
        keys[seq] = (fr << 43) | ((u64)vid << 18) | (u64)seq;
    }
}

__global__ void k_padkeys(u64* keys, const u32* mtp)
{
    int i = blockIdx.x * blockDim.x + threadIdx.x;
    if (i >= NPAD) return;
    if ((u32)i >= mtp[0]) keys[i] = ~0ULL;
}

// ---------------- bitonic sort (u64 keys, NPAD elements) ----------------
__global__ void k_bitonic_fused(u64* keys, u32 k0, u32 k1)
{
    __shared__ u64 sh[2048];
    u32 base = blockIdx.x * 2048;
    int t = threadIdx.x;
    for (int e = t; e < 2048; e += 256) sh[e] = keys[base + e];
    __syncthreads();
    for (u32 k = k0; k <= k1; k <<= 1) {
        u32 j0 = (k >> 1 < 1024u) ? (k >> 1) : 1024u;
        for (u32 j = j0; j >= 1; j >>= 1) {
            for (u32 p = (u32)t; p < 1024; p += 256) {
                u32 i = ((p & ~(j - 1)) << 1) | (p & (j - 1));
                u32 q = i | j;
                bool asc = (((base + i) & k) == 0);
                u64 a = sh[i], c = sh[q];
                if ((a > c) == asc) { sh[i] = c; sh[q] = a; }
            }
            __syncthreads();
        }
    }
    for (int e = t; e < 2048; e += 256) keys[base + e] = sh[e];
}

__global__ void k_bitonic_global(u64* keys, u32 k, u32 j)
{
    u32 p = blockIdx.x * blockDim.x + threadIdx.x;
    u32 i = ((p & ~(j - 1)) << 1) | (p & (j - 1));
    u32 q = i | j;
    bool asc = ((i & k) == 0);
    u64 a = keys[i], c = keys[q];
    if ((a > c) == asc) { keys[i] = c; keys[q] = a; }
}

// ---------------- stage-2 compact cells ----------------
__global__ void k_buildcells(const u64* keys, const u32* koff, const u32* slotsc,
                             u32* cs2, u32* ccnt2, u32* vid2)
{
    int i = blockIdx.x * blockDim.x + threadIdx.x;
    if (i >= NPAD) return;
    u32 Mt = koff[NF * MAXV];
    if ((u32)i >= Mt) return;
    u64 kc = keys[i];
    u32 vid = (u32)((kc >> 18) & 0x1FFFFFFu);
    if (vid == BIG2) return;
    if (i > 0 && (keys[i - 1] >> 18) == (kc >> 18)) return;  // not a head
    u32 f = (u32)(kc >> 43);
    u32 Mb = koff[f * MAXV];
    u32 slot = slotsc[i] - slotsc[Mb];
    if (slot >= (u32)MAXV) return;
    u32 cnt = 1;
    while (cnt < (u32)KK2 && (u32)(i + cnt) < Mt && (keys[i + cnt] >> 18) == (kc >> 18)) cnt++;
    u32 idx = f * MAXV + slot;
    cs2[idx] = (u32)i;
    ccnt2[idx] = cnt;
    vid2[idx] = vid;
}

// ---------------- per-(frame, roi) selection + output ----------------
__global__ void __launch_bounds__(64) k_output(const float* P, const u32* boxp, const u32* koff,
                                               const u32* slotsc, const u32* cs2, const u32* ccnt2,
                                               const u32* vid2, const u64* keys, const u32* kept,
                                               float* out)
{
    __shared__ u32 rlo[MAXROWS];
    __shared__ u32 rlen[MAXROWS];
    __shared__ int sidx[NSAMP];
    __shared__ float feat[KK2 * NSAMP][5];
    __shared__ u32 pmf[KK2 * NSAMP];
    __shared__ int sel[NSAMP];
    __shared__ int nsel;

    int bid = blockIdx.x;
    int tid = threadIdx.x;
    int f = bid / RR, r = bid % RR;
    int b = f / TT, t = f % TT;
    const u32* bp = boxp + bid * 12;
    float bx = __uint_as_float(bp[0]);
    float by = __uint_as_float(bp[1]);
    float cr2 = __uint_as_float(bp[2]);
    float zmax = __uint_as_float(bp[3]);
    int Q1x = (int)bp[7], Q1y = (int)bp[8], irad2 = (int)bp[9];
    u32 Mb = koff[f * MAXV], Me = koff[(f + 1) * MAXV];
    u32 nv2u = slotsc[Me] - slotsc[Mb];
    int nv2 = (nv2u > (u32)MAXV) ? MAXV : (int)nv2u;
    const u32* vidf = vid2 + f * MAXV;

    int cxlo = Q1x - irad2 + 1; if (cxlo < 0) cxlo = 0;
    int cxhi = Q1x + irad2 - 1; if (cxhi > GX2 - 1) cxhi = GX2 - 1;
    int cylo = Q1y - irad2 + 1; if (cylo < 0) cylo = 0;
    int cyhi = Q1y + irad2 - 1; if (cyhi > GY2 - 1) cyhi = GY2 - 1;
    int ny = cyhi - cylo + 1;
    int nrows = (cxlo <= cxhi && cylo <= cyhi && nv2 > 0) ? GZ2 * ny : 0;
    if (nrows > MAXROWS) nrows = MAXROWS;  // defensive; impossible for valid inputs

    // phase A: per-row slot ranges (parallel)
    for (int ri = tid; ri < nrows; ri += 64) {
        int cz = ri / ny, cy = cylo + (ri % ny);
        u32 vlo = ((u32)cz * GY2 + (u32)cy) * GX2 + (u32)cxlo;
        u32 vhi = vlo + (u32)(cxhi - cxlo);
        int lo = 0, hi = nv2;
        while (lo < hi) { int m = (lo + hi) >> 1; if (vidf[m] < vlo) lo = m + 1; else hi = m; }
        int lo2 = lo, hi2 = nv2;
        while (lo2 < hi2) { int m = (lo2 + hi2) >> 1; if (vidf[m] <= vhi) lo2 = m + 1; else hi2 = m; }
        rlo[ri] = (u32)lo;
        rlen[ri] = (u32)(lo2 - lo);
    }
    __syncthreads();

    // phase B: collect first 32 matching slots in ascending slot order, then top_k false-fill
    if (tid == 0) {
        int nt = 0;
        for (int ri = 0; ri < nrows && nt < NSAMP; ri++) {
            u32 lo = rlo[ri], ln = rlen[ri];
            for (u32 a = 0; a < ln && nt < NSAMP; a++) sidx[nt++] = (int)(lo + a);
        }
        int p = 0, s = 0, c = nt;
        while (c < NSAMP) {
            if (p < nt && sidx[p] == s) { p++; s++; continue; }
            sidx[c++] = s++;
        }
    }
    __syncthreads();

    // phase C: gather sv in flat (k2-major) order, evaluate pm (parallel)
    for (int j = tid; j < KK2 * NSAMP; j += 64) {
        int k2 = j >> 5, s = j & 31;
        int slot = sidx[s];
        float px = 0.f, py = 0.f, pz = 0.f, pi = 0.f, pt = 0.f;
        if (slot < nv2) {
            u32 cnt = ccnt2[f * MAXV + slot];
            if ((u32)k2 < cnt) {
                u32 pos = cs2[f * MAXV + slot] + (u32)k2;
                u32 seq = (u32)(keys[pos] & 0x3FFFFu);
                u32 pidx = kept[seq];
                const float* p = P + (size_t)pidx * 6;
                px = p[1]; py = p[2]; pz = p[3]; pi = p[4]; pt = p[5];
            }
        }
        feat[j][0] = px; feat[j][1] = py; feat[j][2] = pz; feat[j][3] = pi; feat[j][4] = pt;
        float ex = px - bx, ey = py - by;
        pmf[j] = (ex * ex + ey * ey < cr2 && pz <= zmax) ? 1u : 0u;
    }
    __syncthreads();

    // phase D: top_k over pm in flat order (serial, tiny)
    if (tid == 0) {
        int c = 0;
        for (int j = 0; j < KK2 * NSAMP && c < NSAMP; j++)
            if (pmf[j]) sel[c++] = j;
        nsel = c;
    }
    __syncthreads();

    // phase E: write 32 rows x 5 feats (parallel)
    int obase = ((b * RR + r) * (TT * NSAMP) + t * NSAMP) * 5;
    for (int w = tid; w < NSAMP * 5; w += 64) {
        int row = w / 5, col = w % 5;
        float v = (row < nsel) ? feat[sel[row]][col] : 0.f;
        out[obase + w] = v;
    }
}

extern "C" void kernel_launch(void* const* d_in, const int* in_sizes, int n_in,
                              void* d_out, int out_size, void* d_ws, size_t ws_size,
                              hipStream_t stream)
{
    const float* P = (const float*)d_in[0];
    const float* traj = (const float*)d_in[1];
    const float* back = (const float*)d_in[2];
    const unsigned char* vlb = (const unsigned char*)d_in[3];
    float* out = (float*)d_out;
    int N = in_sizes[0] / 6;
    if (N > NMAXP) N = NMAXP;

    char* cur = (char*)d_ws;
    auto carve = [&](size_t bytes) -> char* {
        char* p = cur;
        cur += (bytes + 255) & ~(size_t)255;
        return p;
    };
    u32* cnt1 = (u32*)carve((size_t)NC1 * 4);
    u32* starts = (u32*)carve((size_t)(NC1 + 1) * 4);
    u32* flagsc = (u32*)carve((size_t)(NC1 + 1) * 4);
    u32* cursor = (u32*)carve((size_t)NC1 * 4);
    u64* partials = (u64*)carve(1024 * 8);
    u32* pvid = (u32*)carve((size_t)NMAXP * 4);
    u32* ptbuf = (u32*)carve((size_t)NMAXP * 4);
    u32* vcoord = (u32*)carve((size_t)NF * MAXV * 4);
    u32* vcount = (u32*)carve((size_t)NF * MAXV * 4);
    u32* vstart = (u32*)carve((size_t)NF * MAXV * 4);
    u32* npm = (u32*)carve((size_t)NF * MAXV * 4);
    u32* koff = (u32*)carve((size_t)(NF * MAXV + 1) * 4);
    u32* trash = (u32*)carve((size_t)(NF * MAXV + 1) * 4);
    u32* boxp = (u32*)carve((size_t)NF * RR * 12 * 4);
    u32* kept = (u32*)carve((size_t)NMAXP * 4);
    u64* keys = (u64*)carve((size_t)NPAD * 8);
    u32* slotsc = (u32*)carve((size_t)(NPAD + 1) * 4);
    u32* cs2 = (u32*)carve((size_t)NF * MAXV * 4);
    u32* ccnt2 = (u32*)carve((size_t)NF * MAXV * 4);
    u32* vid2 = (u32*)carve((size_t)NF * MAXV * 4);
    if ((size_t)(cur - (char*)d_ws) > ws_size) return;  // insufficient workspace

    hipMemsetAsync(cnt1, 0, (size_t)NC1 * 4, stream);
    hipMemsetAsync(cursor, 0, (size_t)NC1 * 4, stream);

    k_rois<<<(NF * RR + 255) / 256, 256, 0, stream>>>(traj, back, vlb, boxp);
    k_points<<<(N + 255) / 256, 256, 0, stream>>>(P, N, pvid, cnt1);

    {   // scan counts -> starts (lo) + occupancy flags -> flagsc (hi)
        int n = NC1, nb = (n + 2047) / 2048;
        k_scan_partial<0><<<nb, 256, 0, stream>>>(cnt1, nullptr, nullptr, starts, flagsc, partials, n);
        k_scan_level2<<<1, 64, 0, stream>>>(partials, nb, starts, flagsc, n);
        k_scan_addback<<<(n + 255) / 256, 256, 0, stream>>>(starts, flagsc, partials, n);
    }

    k_scatter<<<(N + 255) / 256, 256, 0, stream>>>(pvid, N, starts, cursor, ptbuf);
    k_cellsort<<<(NC1 + 255) / 256, 256, 0, stream>>>(cnt1, starts, ptbuf);
    k_buildvox<<<(NC1 + 255) / 256, 256, 0, stream>>>(cnt1, starts, flagsc, vcoord, vcount, vstart);
    k_vmask<<<(NF * MAXV + 255) / 256, 256, 0, stream>>>(flagsc, vcoord, vcount, boxp, npm);

    {   // scan npm -> koff
        int n = NF * MAXV, nb = (n + 2047) / 2048;
        k_scan_partial<1><<<nb, 256, 0, stream>>>(npm, nullptr, nullptr, koff, trash, partials, n);
        k_scan_level2<<<1, 64, 0, stream>>>(partials, nb, koff, trash, n);
        k_scan_addback<<<(n + 255) / 256, 256, 0, stream>>>(koff, trash, partials, n);
    }

    k_emitkept<<<(NF * MAXV + 255) / 256, 256, 0, stream>>>(P, npm, koff, vstart, ptbuf, kept, keys);
    k_padkeys<<<(NPAD + 255) / 256, 256, 0, stream>>>(keys, koff + NF * MAXV);

    // bitonic sort of NPAD u64 keys
    k_bitonic_fused<<<NPAD / 2048, 256, 0, stream>>>(keys, 2u, 2048u);
    for (u32 k = 4096; k <= (u32)NPAD; k <<= 1) {
        for (u32 j = k >> 1; j >= 2048; j >>= 1)
            k_bitonic_global<<<(NPAD / 2) / 256, 256, 0, stream>>>(keys, k, j);
        k_bitonic_fused<<<NPAD / 2048, 256, 0, stream>>>(keys, k, k);
    }

    {   // scan heads -> slotsc
        int n = NPAD, nb = n / 2048;
        k_scan_partial<2><<<nb, 256, 0, stream>>>(nullptr, keys, koff + NF * MAXV, slotsc, trash, partials, n);
        k_scan_level2<<<1, 64, 0, stream>>>(partials, nb, slotsc, trash, n);
        k_scan_addback<<<(n + 255) / 256, 256, 0, stream>>>(slotsc, trash, partials, n);
    }

    k_buildcells<<<(NPAD + 255) / 256, 256, 0, stream>>>(keys, koff, slotsc, cs2, ccnt2, vid2);
    k_output<<<NF * RR, 64, 0, stream>>>(P, boxp, koff, slotsc, cs2, ccnt2, vid2, keys, kept, out);
}

// Round 2
// 160.661 us; speedup vs baseline: 3.2065x; 3.2065x over previous
//
#include <hip/hip_runtime.h>

typedef unsigned int u32;
typedef unsigned long long u64;

#define BB 2
#define TT 4
#define NF 8            // B*T frames
#define RR 128          // rois
#define NSAMP 32        // num_sample
#define KK2 5           // max points per fine voxel
#define MAXV 50000
#define GX1 376
#define GY1 376
#define C1 141376       // GX1*GY1 (gz=1)
#define NC1 1131008     // NF*C1
#define GX2 752
#define GY2 752
#define GZ2 30
#define WPF 530160      // bitmap words per frame = GX2*GY2*GZ2/32
#define NR2 22560       // GZ2*GY2 fine rows per frame
#define RBW 12          // roibm words per row (376 bits)
#define NPAD 262144
#define NMAXP 262144
#define MAXROWS 1536
#define RPT 6           // rows per thread in k_output (256*6 = 1536)

#define PCX (-75.2f)
#define PCY (-75.2f)
#define PCZ (-2.0f)
#define VS1 0.4f
#define VSH 0.2f
#define VZ1 6.0f

// ---------------- box params ----------------
// layout per (f,r), 12 u32 words:
// 0:bx 1:by 2:cur_r^2 3:zmax (floats); 4:Qx 5:Qy 6:irad 7:Q1x 8:Q1y 9:irad2 (ints)
__global__ void k_rois(const float* traj, const float* back, const unsigned char* vlb, u32* boxp)
{
    int tid = blockIdx.x * blockDim.x + threadIdx.x;
    if (tid >= NF * RR) return;
    // detect valid_length storage: int32 (0/1 -> bytes at %4!=0 are 0) vs uint8/bool
    bool isU8 = false;
    for (int k = 1; k < 64; k++)
        if ((k & 3) && vlb[k]) isU8 = true;
    bool vl = isU8 ? (vlb[tid] != 0) : (((const int*)vlb)[tid] != 0);
    const float* tb = traj + tid * 7;
    const float* bb = back + tid * 7;
    float bx = vl ? (tb[0] + bb[0]) * 0.5f : bb[0];
    float by = vl ? (tb[1] + bb[1]) * 0.5f : bb[1];
    float bz = bb[2], dx = bb[3], dy = bb[4], dz = bb[5];
    float hx = dx * 0.5f, hy = dy * 0.5f;
    float r0 = sqrtf(hx * hx + hy * hy);
    float radf = ceilf(r0 * 1.1f / 0.4f);
    float curr = r0 * 1.1f;
    u32* bp = boxp + tid * 12;
    bp[0] = __float_as_uint(bx);
    bp[1] = __float_as_uint(by);
    bp[2] = __float_as_uint(curr * curr);
    bp[3] = __float_as_uint(bz + dz * 0.6f);
    bp[4] = (u32)(int)floorf((bx - PCX) / VS1);
    bp[5] = (u32)(int)floorf((by - PCY) / VS1);
    bp[6] = (u32)(int)radf;
    bp[7] = (u32)(int)floorf((bx - PCX) / VSH);
    bp[8] = (u32)(int)floorf((by - PCY) / VSH);
    bp[9] = (u32)(2 * (int)radf);
}

// ---------------- rasterize stage-1 roi windows into per-frame bitmap ----------------
__global__ void k_roiraster(const u32* boxp, u32* roibm)
{
    int tid = blockIdx.x * blockDim.x + threadIdx.x;
    if (tid >= NF * RR) return;
    const u32* bp = boxp + tid * 12;
    int f = tid / RR;
    int Qx = (int)bp[4], Qy = (int)bp[5], ir = (int)bp[6];
    int xlo = Qx - ir + 1; if (xlo < 0) xlo = 0;
    int xhi = Qx + ir - 1; if (xhi > GX1 - 1) xhi = GX1 - 1;
    int ylo = Qy - ir + 1; if (ylo < 0) ylo = 0;
    int yhi = Qy + ir - 1; if (yhi > GY1 - 1) yhi = GY1 - 1;
    if (xlo > xhi || ylo > yhi) return;
    int w0 = xlo >> 5, w1 = xhi >> 5;
    for (int cy = ylo; cy <= yhi; cy++) {
        u32* row = roibm + (size_t)f * (GY1 * RBW) + cy * RBW;
        for (int w = w0; w <= w1; w++) {
            int lo = xlo - (w << 5); if (lo < 0) lo = 0;
            int hi = xhi - (w << 5); if (hi > 31) hi = 31;
            u32 m = (hi == 31 ? 0xFFFFFFFFu : ((1u << (hi + 1)) - 1u)) & ~((1u << lo) - 1u);
            atomicOr(&row[w], m);
        }
    }
}

// ---------------- stage-1 voxelize ----------------
__global__ void k_points(const float* P, int n, u32* pvid, u32* cnt1)
{
    int i = blockIdx.x * blockDim.x + threadIdx.x;
    if (i >= n) return;
    const float* p = P + (size_t)i * 6;
    float bsf = p[0], x = p[1], y = p[2], z = p[3], tt = p[5];
    u32 g = 0xFFFFFFFFu;
    int b = (int)bsf;
    int t = (int)floorf(tt * 10.0f + 0.5f);
    if (bsf == (float)b && b >= 0 && b < BB && t >= 0 && t < TT &&
        fabsf(tt - 0.1f * (float)t) < 0.001f) {
        float fx = floorf((x - PCX) / VS1);
        float fy = floorf((y - PCY) / VS1);
        float fz = floorf((z - PCZ) / VZ1);
        if (fx >= 0.f && fx < (float)GX1 && fy >= 0.f && fy < (float)GY1 && fz == 0.f) {
            g = (u32)((b * TT + t) * C1) + (u32)fy * GX1 + (u32)fx;
        }
    }
    pvid[i] = g;
    if (g != 0xFFFFFFFFu) atomicAdd(&cnt1[g], 1u);
}

// ---------------- hierarchical exclusive scan ----------------
// MODE 0: in=counts -> lo:prefix(count) hi:prefix(count!=0)
// MODE 1: in=u32    -> lo:prefix(in)
// MODE 3: in=bitmap -> lo:prefix(popcount)
template <int MODE>
__global__ void k_scan_partial(const u32* in, u32* out_lo, u32* out_hi, u64* partials, int n)
{
    __shared__ u64 sh[256];
    int blk = blockIdx.x, t = threadIdx.x;
    int base = blk * 2048 + t * 8;
    u32 v[8];
    if (base + 8 <= n) {
        uint4 a = *(const uint4*)(in + base);
        uint4 bq = *(const uint4*)(in + base + 4);
        v[0] = a.x; v[1] = a.y; v[2] = a.z; v[3] = a.w;
        v[4] = bq.x; v[5] = bq.y; v[6] = bq.z; v[7] = bq.w;
    } else {
        #pragma unroll
        for (int e = 0; e < 8; e++) { int i = base + e; v[e] = (i < n) ? in[i] : 0u; }
    }
    u64 pref[8]; u64 sum = 0;
    #pragma unroll
    for (int e = 0; e < 8; e++) {
        u64 val;
        if (MODE == 0)      val = (u64)v[e] | ((u64)(v[e] != 0u) << 32);
        else if (MODE == 1) val = v[e];
        else                val = (u32)__popc(v[e]);
        pref[e] = sum; sum += val;
    }
    sh[t] = sum;
    __syncthreads();
    for (int off = 1; off < 256; off <<= 1) {
        u64 y = (t >= off) ? sh[t - off] : 0;
        __syncthreads();
        sh[t] += y;
        __syncthreads();
    }
    u64 texcl = sh[t] - sum;
    if (t == 255) partials[blk] = sh[255];
    if (base + 8 <= n) {
        u32 lo_a[8], hi_a[8];
        #pragma unroll
        for (int e = 0; e < 8; e++) {
            u64 x = texcl + pref[e];
            lo_a[e] = (u32)x; hi_a[e] = (u32)(x >> 32);
        }
        *(uint4*)(out_lo + base)     = make_uint4(lo_a[0], lo_a[1], lo_a[2], lo_a[3]);
        *(uint4*)(out_lo + base + 4) = make_uint4(lo_a[4], lo_a[5], lo_a[6], lo_a[7]);
        if (MODE == 0) {
            *(uint4*)(out_hi + base)     = make_uint4(hi_a[0], hi_a[1], hi_a[2], hi_a[3]);
            *(uint4*)(out_hi + base + 4) = make_uint4(hi_a[4], hi_a[5], hi_a[6], hi_a[7]);
        }
    } else {
        for (int e = 0; e < 8; e++) {
            int i = base + e;
            if (i < n) {
                u64 x = texcl + pref[e];
                out_lo[i] = (u32)x;
                if (MODE == 0) out_hi[i] = (u32)(x >> 32);
            }
        }
    }
}

__global__ void k_scan_level2(u64* partials, int nb, u32* out_lo, u32* out_hi, int n)
{
    __shared__ u64 sh[256];
    int t = threadIdx.x;
    u64 loc[16]; u64 sum = 0;
    int base = t * 16;
    #pragma unroll
    for (int e = 0; e < 16; e++) {
        u64 v = (base + e < nb) ? partials[base + e] : 0;
        loc[e] = sum; sum += v;
    }
    sh[t] = sum;
    __syncthreads();
    for (int off = 1; off < 256; off <<= 1) {
        u64 y = (t >= off) ? sh[t - off] : 0;
        __syncthreads();
        sh[t] += y;
        __syncthreads();
    }
    u64 excl = sh[t] - sum;
    #pragma unroll
    for (int e = 0; e < 16; e++)
        if (base + e < nb) partials[base + e] = excl + loc[e];
    if (t == 255) {
        u64 tot = sh[255];
        out_lo[n] = (u32)tot;
        if (out_hi) out_hi[n] = (u32)(tot >> 32);
    }
}

template <bool HI>
__global__ void k_scan_addback(u32* out_lo, u32* out_hi, const u64* partials, int n)
{
    int base = blockIdx.x * 2048 + threadIdx.x * 8;
    if (base >= n) return;
    u64 bsum = partials[blockIdx.x];
    if (bsum == 0) return;
    u32 blo = (u32)bsum, bhi = (u32)(bsum >> 32);
    if (base + 8 <= n) {
        uint4 a = *(uint4*)(out_lo + base);
        uint4 c = *(uint4*)(out_lo + base + 4);
        a.x += blo; a.y += blo; a.z += blo; a.w += blo;
        c.x += blo; c.y += blo; c.z += blo; c.w += blo;
        *(uint4*)(out_lo + base) = a;
        *(uint4*)(out_lo + base + 4) = c;
        if (HI) {
            uint4 h1 = *(uint4*)(out_hi + base);
            uint4 h2 = *(uint4*)(out_hi + base + 4);
            h1.x += bhi; h1.y += bhi; h1.z += bhi; h1.w += bhi;
            h2.x += bhi; h2.y += bhi; h2.z += bhi; h2.w += bhi;
            *(uint4*)(out_hi + base) = h1;
            *(uint4*)(out_hi + base + 4) = h2;
        }
    } else {
        for (int e = 0; e < 8; e++) {
            int i = base + e;
            if (i < n) { out_lo[i] += blo; if (HI) out_hi[i] += bhi; }
        }
    }
}

// ---------------- stage-1 scatter ----------------
__global__ void k_scatter(const u32* pvid, int n, const u32* starts, u32* cursor, u32* ptbuf)
{
    int i = blockIdx.x * blockDim.x + threadIdx.x;
    if (i >= n) return;
    u32 g = pvid[i];
    if (g == 0xFFFFFFFFu) return;
    u32 pos = atomicAdd(&cursor[g], 1u);
    ptbuf[starts[g] + pos] = (u32)i;
}

// ---------------- fused: per-cell sort + voxel build + roi mask ----------------
__global__ void k_cells(const u32* cnt1, const u32* starts, const u32* flagsc,
                        const u32* roibm, u32* ptbuf, u32* npm, u32* vstart)
{
    int c = blockIdx.x * blockDim.x + threadIdx.x;
    if (c >= NC1) return;
    u32 n = cnt1[c];
    if (!n) return;
    int f = c / C1, lv = c % C1;
    u32 slot = flagsc[c] - flagsc[f * C1];
    if (slot >= MAXV) return;
    int cx = lv % GX1, cy = lv / GX1;
    u32 idx = (u32)f * MAXV + slot;
    u32 s0 = starts[c];
    vstart[idx] = s0;
    u32 bit = (roibm[(size_t)f * (GY1 * RBW) + cy * RBW + (cx >> 5)] >> (cx & 31)) & 1u;
    if (!bit) return;  // npm stays 0 from memset
    npm[idx] = n < 32u ? n : 32u;
    // stable order within voxel = ascending point index: insertion sort
    for (u32 a = 1; a < n; a++) {
        u32 v = ptbuf[s0 + a];
        int bp2 = (int)a;
        while (bp2 > 0 && ptbuf[s0 + bp2 - 1] > v) { ptbuf[s0 + bp2] = ptbuf[s0 + bp2 - 1]; bp2--; }
        ptbuf[s0 + bp2] = v;
    }
}

// ---------------- emit kept points, mark fine-voxel bitmap ----------------
__global__ void k_emitkept(const float* P, const u32* npm, const u32* koff, const u32* vstart,
                           const u32* ptbuf, u32* kept, u32* fvid, u32* bitmap)
{
    int idx = blockIdx.x * blockDim.x + threadIdx.x;
    if (idx >= NF * MAXV) return;
    u32 m = npm[idx];
    if (!m) return;
    u32 base = koff[idx];
    u32 vs = vstart[idx];
    u32 f = (u32)idx / MAXV;
    for (u32 r = 0; r < m; r++) {
        u32 pidx = ptbuf[vs + r];
        u32 seq = base + r;
        kept[seq] = pidx;
        const float* p = P + (size_t)pidx * 6;
        float fx = floorf((p[1] - PCX) / VSH);
        float fy = floorf((p[2] - PCY) / VSH);
        float fz = floorf((p[3] - PCZ) / VSH);
        u32 pk = 0xFFFFFFFFu;
        if (fx >= 0.f && fx < (float)GX2 && fy >= 0.f && fy < (float)GY2 &&
            fz >= 0.f && fz < (float)GZ2) {
            u32 vid = ((u32)fz * GY2 + (u32)fy) * GX2 + (u32)fx;
            pk = (f << 25) | vid;
            atomicOr(&bitmap[f * WPF + (vid >> 5)], 1u << (vid & 31));
        }
        fvid[seq] = pk;
    }
}

// ---------------- insert kept seqs into per-voxel 5-min sorted arrays ----------------
__global__ void k_insert(const u32* fvid, const u32* koffend, const u32* bitmap,
                         const u32* wordpref, u32* slotseq)
{
    u32 i = blockIdx.x * blockDim.x + threadIdx.x;
    u32 Mt = koffend[0];
    if (i >= Mt) return;
    u32 pk = fvid[i];
    if (pk == 0xFFFFFFFFu) return;
    u32 f = pk >> 25, vid = pk & 0x1FFFFFFu;
    u32 gw = f * WPF + (vid >> 5);
    u32 slot = wordpref[gw] - wordpref[f * WPF] +
               (u32)__popc(bitmap[gw] & ((1u << (vid & 31)) - 1u));
    if (slot >= (u32)MAXV) return;
    u32* arr = slotseq + (size_t)(f * MAXV + slot) * KK2;
    u32 val = i;
    #pragma unroll
    for (int j = 0; j < KK2; j++) {
        u32 old = atomicMin(&arr[j], val);
        if (old == 0xFFFFFFFFu) break;     // landed in empty slot
        val = old > val ? old : val;       // carry displaced value
    }
}

// ---------------- fill per-frame slot->vid table + row counts ----------------
__global__ void k_fillvid(const u32* bitmap, const u32* wordpref, u32* vid2, u32* rowcnt)
{
    u32 gw = blockIdx.x * blockDim.x + threadIdx.x;
    if (gw >= (u32)NF * WPF) return;
    u32 bits = bitmap[gw];
    if (!bits) return;
    u32 f = gw / WPF;
    u32 base = wordpref[gw] - wordpref[f * WPF];
    u32 vid0 = (gw - f * WPF) << 5;
    while (bits) {
        u32 bpos = (u32)__ffs(bits) - 1u;
        u32 slot = base++;
        if (slot < (u32)MAXV) {
            u32 vid = vid0 + bpos;
            vid2[f * MAXV + slot] = vid;
            atomicAdd(&rowcnt[f * NR2 + vid / GX2], 1u);
        }
        bits &= bits - 1u;
    }
}

// ---------------- per-(frame, roi) selection + output ----------------
__global__ void __launch_bounds__(256) k_output(const float* P, const u32* boxp,
    const u32* rowstart, const u32* vid2, const u32* slotseq, const u32* kept, float* out)
{
    __shared__ u32 rlo_s[MAXROWS];
    __shared__ u32 rpref_s[MAXROWS];
    __shared__ u32 ssum[256];
    __shared__ int sidx[NSAMP];
    __shared__ float feat[KK2 * NSAMP][5];
    __shared__ u32 pmf[KK2 * NSAMP];
    __shared__ int sel[NSAMP];
    __shared__ int nsel_s;
    __shared__ u32 M_s;

    int bid = blockIdx.x, tid = threadIdx.x;
    int f = bid / RR, r = bid % RR;
    int b = f / TT, t = f % TT;
    const u32* bp = boxp + bid * 12;
    float bx = __uint_as_float(bp[0]);
    float by = __uint_as_float(bp[1]);
    float cr2 = __uint_as_float(bp[2]);
    float zmax = __uint_as_float(bp[3]);
    int Q1x = (int)bp[7], Q1y = (int)bp[8], irad2 = (int)bp[9];

    u32 fb = rowstart[f * NR2];
    u32 fe = rowstart[(f + 1) * NR2];
    int nv2 = (int)(fe - fb);
    const u32* vidf = vid2 + f * MAXV;

    int cxlo = Q1x - irad2 + 1; if (cxlo < 0) cxlo = 0;
    int cxhi = Q1x + irad2 - 1; if (cxhi > GX2 - 1) cxhi = GX2 - 1;
    int cylo = Q1y - irad2 + 1; if (cylo < 0) cylo = 0;
    int cyhi = Q1y + irad2 - 1; if (cyhi > GY2 - 1) cyhi = GY2 - 1;
    int ny = cyhi - cylo + 1;
    int nrows = (cxlo <= cxhi && cylo <= cyhi && nv2 > 0) ? GZ2 * ny : 0;
    if (nrows > MAXROWS) nrows = MAXROWS;

    // phase A: per-row slot ranges via rowstart table (blocked per thread)
    u32 myrlo[RPT], myrpref[RPT];
    u32 lsum = 0;
    #pragma unroll
    for (int e = 0; e < RPT; e++) {
        int ri = tid * RPT + e;
        myrpref[e] = lsum;
        myrlo[e] = 0;
        if (ri < nrows) {
            int cz = ri / ny, cy = cylo + (ri - cz * ny);
            int gr = f * NR2 + cz * GY2 + cy;
            u32 lo = rowstart[gr] - fb, hi = rowstart[gr + 1] - fb;
            u32 vlo = ((u32)cz * GY2 + (u32)cy) * GX2 + (u32)cxlo;
            u32 vhi = vlo + (u32)(cxhi - cxlo);
            u32 s0 = lo, e0 = hi;
            while (s0 < e0) { u32 m = (s0 + e0) >> 1; if (vidf[m] < vlo) s0 = m + 1; else e0 = m; }
            u32 s1 = s0, e1 = hi;
            while (s1 < e1) { u32 m = (s1 + e1) >> 1; if (vidf[m] <= vhi) s1 = m + 1; else e1 = m; }
            myrlo[e] = s0;
            lsum += s1 - s0;
        }
    }
    ssum[tid] = lsum;
    __syncthreads();
    for (int off = 1; off < 256; off <<= 1) {
        u32 y = (tid >= off) ? ssum[tid - off] : 0;
        __syncthreads();
        ssum[tid] += y;
        __syncthreads();
    }
    u32 texcl = ssum[tid] - lsum;
    if (tid == 255) M_s = ssum[255];
    #pragma unroll
    for (int e = 0; e < RPT; e++) {
        int ri = tid * RPT + e;
        rlo_s[ri] = myrlo[e];
        rpref_s[ri] = texcl + myrpref[e];
    }
    __syncthreads();

    u32 M = M_s;
    int nt = (int)(M < (u32)NSAMP ? M : (u32)NSAMP);
    // phase B1: matched slots in ascending order (rows ascending => slots ascending)
    if (tid < nt) {
        int lo = 0, hi = nrows - 1;
        while (lo < hi) { int m = (lo + hi + 1) >> 1; if (rpref_s[m] <= (u32)tid) lo = m; else hi = m - 1; }
        sidx[tid] = (int)(rlo_s[lo] + ((u32)tid - rpref_s[lo]));
    }
    __syncthreads();
    // phase B2: top_k false-fill with lowest non-matching slot indices
    if (tid == 0) {
        int c = nt, p = 0, s = 0;
        while (c < NSAMP) {
            if (p < nt && sidx[p] == s) { p++; s++; continue; }
            sidx[c++] = s++;
        }
    }
    __syncthreads();

    // phase C: gather sv in flat (k2-major) order, evaluate pm
    for (int j = tid; j < KK2 * NSAMP; j += 256) {
        int k2 = j >> 5, s = j & 31;
        int slot = sidx[s];
        float px = 0.f, py = 0.f, pz = 0.f, pi = 0.f, pt = 0.f;
        if (slot < nv2) {
            u32 seq = slotseq[(size_t)(f * MAXV + slot) * KK2 + k2];
            if (seq != 0xFFFFFFFFu) {
                u32 pidx = kept[seq];
                const float* p = P + (size_t)pidx * 6;
                px = p[1]; py = p[2]; pz = p[3]; pi = p[4]; pt = p[5];
            }
        }
        feat[j][0] = px; feat[j][1] = py; feat[j][2] = pz; feat[j][3] = pi; feat[j][4] = pt;
        float ex = px - bx, ey = py - by;
        pmf[j] = (ex * ex + ey * ey < cr2 && pz <= zmax) ? 1u : 0u;
    }
    __syncthreads();

    // phase D: top_k over pm in flat order
    if (tid == 0) {
        int c = 0;
        for (int j = 0; j < KK2 * NSAMP && c < NSAMP; j++)
            if (pmf[j]) sel[c++] = j;
        nsel_s = c;
    }
    __syncthreads();

    // phase E: write 32 rows x 5 feats
    int obase = ((b * RR + r) * (TT * NSAMP) + t * NSAMP) * 5;
    for (int w = tid; w < NSAMP * 5; w += 256) {
        int row = w / 5, col = w % 5;
        float v = (row < nsel_s) ? feat[sel[row]][col] : 0.f;
        out[obase + w] = v;
    }
}

extern "C" void kernel_launch(void* const* d_in, const int* in_sizes, int n_in,
                              void* d_out, int out_size, void* d_ws, size_t ws_size,
                              hipStream_t stream)
{
    const float* P = (const float*)d_in[0];
    const float* traj = (const float*)d_in[1];
    const float* back = (const float*)d_in[2];
    const unsigned char* vlb = (const unsigned char*)d_in[3];
    float* out = (float*)d_out;
    int N = in_sizes[0] / 6;
    if (N > NMAXP) N = NMAXP;

    char* cur = (char*)d_ws;
    auto carve = [&](size_t bytes) -> char* {
        char* p = cur;
        cur += (bytes + 255) & ~(size_t)255;
        return p;
    };

    // ---- zone A (single memset-0), order matters ----
    char* zoneA = cur;
    u32* cnt1   = (u32*)carve((size_t)NC1 * 4);
    u32* cursor = (u32*)carve((size_t)NC1 * 4);
    u32* flagsc = (u32*)carve((size_t)(NC1 + 1) * 4);
    u32* starts = (u32*)carve((size_t)(NC1 + 1) * 4);
    u32* npm    = (u32*)carve((size_t)NF * MAXV * 4);
    u32* rowcnt = (u32*)carve((size_t)NF * NR2 * 4);
    u32* roibm  = (u32*)carve((size_t)NF * GY1 * RBW * 4);
    u32* bitmap = (u32*)carve((size_t)NF * WPF * 4);
    size_t zoneA_bytes = (size_t)(cur - zoneA);
    // wordpref aliases cnt1+cursor+flagsc+starts (18.1MB >= 17MB), all dead before it's written
    u32* wordpref = (u32*)zoneA;

    u64* partials = (u64*)carve(4096 * 8);
    u32* pvid     = (u32*)carve((size_t)NMAXP * 4);
    u32* ptbuf    = (u32*)carve((size_t)NMAXP * 4);
    u32* vstart   = (u32*)carve((size_t)NF * MAXV * 4);
    u32* koff     = (u32*)carve((size_t)(NF * MAXV + 1) * 4);
    u32* boxp     = (u32*)carve((size_t)NF * RR * 12 * 4);
    u32* kept     = (u32*)carve((size_t)NMAXP * 4);
    u32* fvid     = (u32*)carve((size_t)NMAXP * 4);
    u32* slotseq  = (u32*)carve((size_t)NF * MAXV * KK2 * 4);
    u32* vid2     = (u32*)carve((size_t)NF * MAXV * 4);
    u32* rowstart = (u32*)carve((size_t)(NF * NR2 + 1) * 4);
    if ((size_t)(cur - (char*)d_ws) > ws_size) return;  // insufficient workspace

    hipMemsetAsync(zoneA, 0, zoneA_bytes, stream);
    hipMemsetAsync(slotseq, 0xFF, (size_t)NF * MAXV * KK2 * 4, stream);

    auto scan = [&](int mode, const u32* in, u32* lo, u32* hi, int n) {
        int nb = (n + 2047) / 2048;
        if (mode == 0)      k_scan_partial<0><<<nb, 256, 0, stream>>>(in, lo, hi, partials, n);
        else if (mode == 1) k_scan_partial<1><<<nb, 256, 0, stream>>>(in, lo, hi, partials, n);
        else                k_scan_partial<3><<<nb, 256, 0, stream>>>(in, lo, hi, partials, n);
        k_scan_level2<<<1, 256, 0, stream>>>(partials, nb, lo, hi, n);
        if (mode == 0) k_scan_addback<true><<<nb, 256, 0, stream>>>(lo, hi, partials, n);
        else           k_scan_addback<false><<<nb, 256, 0, stream>>>(lo, nullptr, partials, n);
    };

    k_rois<<<(NF * RR + 255) / 256, 256, 0, stream>>>(traj, back, vlb, boxp);
    k_roiraster<<<(NF * RR + 255) / 256, 256, 0, stream>>>(boxp, roibm);
    k_points<<<(N + 255) / 256, 256, 0, stream>>>(P, N, pvid, cnt1);

    scan(0, cnt1, starts, flagsc, NC1);

    k_scatter<<<(N + 255) / 256, 256, 0, stream>>>(pvid, N, starts, cursor, ptbuf);
    k_cells<<<(NC1 + 255) / 256, 256, 0, stream>>>(cnt1, starts, flagsc, roibm, ptbuf, npm, vstart);

    scan(1, npm, koff, nullptr, NF * MAXV);

    k_emitkept<<<(NF * MAXV + 255) / 256, 256, 0, stream>>>(P, npm, koff, vstart, ptbuf, kept, fvid, bitmap);

    scan(3, bitmap, wordpref, nullptr, NF * WPF);

    k_insert<<<NPAD / 256, 256, 0, stream>>>(fvid, koff + NF * MAXV, bitmap, wordpref, slotseq);
    k_fillvid<<<((u32)NF * WPF + 255) / 256, 256, 0, stream>>>(bitmap, wordpref, vid2, rowcnt);

    scan(1, rowcnt, rowstart, nullptr, NF * NR2);

    k_output<<<NF * RR, 256, 0, stream>>>(P, boxp, rowstart, vid2, slotseq, kept, out);
}

// Round 3
// 155.147 us; speedup vs baseline: 3.3205x; 1.0355x over previous
//
#include <hip/hip_runtime.h>

typedef unsigned int u32;
typedef unsigned long long u64;

#define BB 2
#define TT 4
#define NF 8            // B*T frames
#define RR 128          // rois
#define NSAMP 32        // num_sample
#define KK2 5           // max points per fine voxel
#define MAXV 50000
#define GX1 376
#define GY1 376
#define C1 141376       // GX1*GY1 (gz=1)
#define NC1 1131008     // NF*C1
#define GX2 752
#define GY2 752
#define GZ2 30
#define WPF 530160      // bitmap words per frame = GX2*GY2*GZ2/32
#define NR2 22560       // GZ2*GY2 fine rows per frame
#define RBW 12          // roibm words per row (376 bits)
#define NPAD 262144
#define NMAXP 262144
#define MAXROWS 1536
#define RPT 6           // rows per thread in k_output (256*6 = 1536)

#define PCX (-75.2f)
#define PCY (-75.2f)
#define PCZ (-2.0f)
#define VS1 0.4f
#define VSH 0.2f
#define VZ1 6.0f

// ---------------- workspace init (replaces slow rocclr fills) ----------------
// z0,z1: zero segments; f2: 0xFF segment. Counts are in uint4 units.
__global__ void k_init(u32* z0, u32 n0, u32* z1, u32 n1, u32* f2, u32 n2)
{
    u32 tid = blockIdx.x * blockDim.x + threadIdx.x;
    u32 stride = gridDim.x * blockDim.x;
    uint4 zz = make_uint4(0u, 0u, 0u, 0u);
    uint4 fv = make_uint4(~0u, ~0u, ~0u, ~0u);
    for (u32 i = tid; i < n0; i += stride) ((uint4*)z0)[i] = zz;
    for (u32 i = tid; i < n1; i += stride) ((uint4*)z1)[i] = zz;
    for (u32 i = tid; i < n2; i += stride) ((uint4*)f2)[i] = fv;
}

// ---------------- box params + stage-1 roi raster (fused) ----------------
// boxp layout per (f,r), 12 u32 words:
// 0:bx 1:by 2:cur_r^2 3:zmax (floats); 4:Qx 5:Qy 6:irad 7:Q1x 8:Q1y 9:irad2 (ints)
__global__ void k_roisraster(const float* traj, const float* back, const unsigned char* vlb,
                             u32* boxp, u32* roibm)
{
    int tid = blockIdx.x * blockDim.x + threadIdx.x;
    if (tid >= NF * RR) return;
    // detect valid_length storage: int32 (0/1 -> bytes at %4!=0 are 0) vs uint8/bool
    bool isU8 = false;
    for (int k = 1; k < 64; k++)
        if ((k & 3) && vlb[k]) isU8 = true;
    bool vl = isU8 ? (vlb[tid] != 0) : (((const int*)vlb)[tid] != 0);
    const float* tb = traj + tid * 7;
    const float* bb = back + tid * 7;
    float bx = vl ? (tb[0] + bb[0]) * 0.5f : bb[0];
    float by = vl ? (tb[1] + bb[1]) * 0.5f : bb[1];
    float bz = bb[2], dx = bb[3], dy = bb[4], dz = bb[5];
    float hx = dx * 0.5f, hy = dy * 0.5f;
    float r0 = sqrtf(hx * hx + hy * hy);
    float radf = ceilf(r0 * 1.1f / 0.4f);
    float curr = r0 * 1.1f;
    u32* bp = boxp + tid * 12;
    int Qx = (int)floorf((bx - PCX) / VS1);
    int Qy = (int)floorf((by - PCY) / VS1);
    int ir = (int)radf;
    bp[0] = __float_as_uint(bx);
    bp[1] = __float_as_uint(by);
    bp[2] = __float_as_uint(curr * curr);
    bp[3] = __float_as_uint(bz + dz * 0.6f);
    bp[4] = (u32)Qx;
    bp[5] = (u32)Qy;
    bp[6] = (u32)ir;
    bp[7] = (u32)(int)floorf((bx - PCX) / VSH);
    bp[8] = (u32)(int)floorf((by - PCY) / VSH);
    bp[9] = (u32)(2 * ir);

    // rasterize this roi's stage-1 window into the per-frame bitmap
    int f = tid / RR;
    int xlo = Qx - ir + 1; if (xlo < 0) xlo = 0;
    int xhi = Qx + ir - 1; if (xhi > GX1 - 1) xhi = GX1 - 1;
    int ylo = Qy - ir + 1; if (ylo < 0) ylo = 0;
    int yhi = Qy + ir - 1; if (yhi > GY1 - 1) yhi = GY1 - 1;
    if (xlo > xhi || ylo > yhi) return;
    int w0 = xlo >> 5, w1 = xhi >> 5;
    for (int cy = ylo; cy <= yhi; cy++) {
        u32* row = roibm + (size_t)f * (GY1 * RBW) + cy * RBW;
        for (int w = w0; w <= w1; w++) {
            int lo = xlo - (w << 5); if (lo < 0) lo = 0;
            int hi = xhi - (w << 5); if (hi > 31) hi = 31;
            u32 m = (hi == 31 ? 0xFFFFFFFFu : ((1u << (hi + 1)) - 1u)) & ~((1u << lo) - 1u);
            atomicOr(&row[w], m);
        }
    }
}

// ---------------- stage-1 voxelize ----------------
__global__ void k_points(const float* P, int n, u32* pvid, u32* cnt1)
{
    int i = blockIdx.x * blockDim.x + threadIdx.x;
    if (i >= n) return;
    const float* p = P + (size_t)i * 6;
    float bsf = p[0], x = p[1], y = p[2], z = p[3], tt = p[5];
    u32 g = 0xFFFFFFFFu;
    int b = (int)bsf;
    int t = (int)floorf(tt * 10.0f + 0.5f);
    if (bsf == (float)b && b >= 0 && b < BB && t >= 0 && t < TT &&
        fabsf(tt - 0.1f * (float)t) < 0.001f) {
        float fx = floorf((x - PCX) / VS1);
        float fy = floorf((y - PCY) / VS1);
        float fz = floorf((z - PCZ) / VZ1);
        if (fx >= 0.f && fx < (float)GX1 && fy >= 0.f && fy < (float)GY1 && fz == 0.f) {
            g = (u32)((b * TT + t) * C1) + (u32)fy * GX1 + (u32)fx;
        }
    }
    pvid[i] = g;
    if (g != 0xFFFFFFFFu) atomicAdd(&cnt1[g], 1u);
}

// ---------------- hierarchical exclusive scan ----------------
// MODE 0: in=counts -> lo:prefix(count) hi:prefix(count!=0)
// MODE 1: in=u32    -> lo:prefix(in)
// MODE 3: in=bitmap -> lo:prefix(popcount)
template <int MODE>
__global__ void k_scan_partial(const u32* in, u32* out_lo, u32* out_hi, u64* partials, int n)
{
    __shared__ u64 sh[256];
    int blk = blockIdx.x, t = threadIdx.x;
    int base = blk * 2048 + t * 8;
    u32 v[8];
    if (base + 8 <= n) {
        uint4 a = *(const uint4*)(in + base);
        uint4 bq = *(const uint4*)(in + base + 4);
        v[0] = a.x; v[1] = a.y; v[2] = a.z; v[3] = a.w;
        v[4] = bq.x; v[5] = bq.y; v[6] = bq.z; v[7] = bq.w;
    } else {
        #pragma unroll
        for (int e = 0; e < 8; e++) { int i = base + e; v[e] = (i < n) ? in[i] : 0u; }
    }
    u64 pref[8]; u64 sum = 0;
    #pragma unroll
    for (int e = 0; e < 8; e++) {
        u64 val;
        if (MODE == 0)      val = (u64)v[e] | ((u64)(v[e] != 0u) << 32);
        else if (MODE == 1) val = v[e];
        else                val = (u32)__popc(v[e]);
        pref[e] = sum; sum += val;
    }
    sh[t] = sum;
    __syncthreads();
    for (int off = 1; off < 256; off <<= 1) {
        u64 y = (t >= off) ? sh[t - off] : 0;
        __syncthreads();
        sh[t] += y;
        __syncthreads();
    }
    u64 texcl = sh[t] - sum;
    if (t == 255) partials[blk] = sh[255];
    if (base + 8 <= n) {
        u32 lo_a[8], hi_a[8];
        #pragma unroll
        for (int e = 0; e < 8; e++) {
            u64 x = texcl + pref[e];
            lo_a[e] = (u32)x; hi_a[e] = (u32)(x >> 32);
        }
        *(uint4*)(out_lo + base)     = make_uint4(lo_a[0], lo_a[1], lo_a[2], lo_a[3]);
        *(uint4*)(out_lo + base + 4) = make_uint4(lo_a[4], lo_a[5], lo_a[6], lo_a[7]);
        if (MODE == 0) {
            *(uint4*)(out_hi + base)     = make_uint4(hi_a[0], hi_a[1], hi_a[2], hi_a[3]);
            *(uint4*)(out_hi + base + 4) = make_uint4(hi_a[4], hi_a[5], hi_a[6], hi_a[7]);
        }
    } else {
        for (int e = 0; e < 8; e++) {
            int i = base + e;
            if (i < n) {
                u64 x = texcl + pref[e];
                out_lo[i] = (u32)x;
                if (MODE == 0) out_hi[i] = (u32)(x >> 32);
            }
        }
    }
}

__global__ void k_scan_level2(u64* partials, int nb, u32* out_lo, u32* out_hi, int n)
{
    __shared__ u64 sh[256];
    int t = threadIdx.x;
    u64 loc[16]; u64 sum = 0;
    int base = t * 16;
    #pragma unroll
    for (int e = 0; e < 16; e++) {
        u64 v = (base + e < nb) ? partials[base + e] : 0;
        loc[e] = sum; sum += v;
    }
    sh[t] = sum;
    __syncthreads();
    for (int off = 1; off < 256; off <<= 1) {
        u64 y = (t >= off) ? sh[t - off] : 0;
        __syncthreads();
        sh[t] += y;
        __syncthreads();
    }
    u64 excl = sh[t] - sum;
    #pragma unroll
    for (int e = 0; e < 16; e++)
        if (base + e < nb) partials[base + e] = excl + loc[e];
    if (t == 255) {
        u64 tot = sh[255];
        out_lo[n] = (u32)tot;
        if (out_hi) out_hi[n] = (u32)(tot >> 32);
    }
}

template <bool HI>
__global__ void k_scan_addback(u32* out_lo, u32* out_hi, const u64* partials, int n)
{
    int base = blockIdx.x * 2048 + threadIdx.x * 8;
    if (base >= n) return;
    u64 bsum = partials[blockIdx.x];
    if (bsum == 0) return;
    u32 blo = (u32)bsum, bhi = (u32)(bsum >> 32);
    if (base + 8 <= n) {
        uint4 a = *(uint4*)(out_lo + base);
        uint4 c = *(uint4*)(out_lo + base + 4);
        a.x += blo; a.y += blo; a.z += blo; a.w += blo;
        c.x += blo; c.y += blo; c.z += blo; c.w += blo;
        *(uint4*)(out_lo + base) = a;
        *(uint4*)(out_lo + base + 4) = c;
        if (HI) {
            uint4 h1 = *(uint4*)(out_hi + base);
            uint4 h2 = *(uint4*)(out_hi + base + 4);
            h1.x += bhi; h1.y += bhi; h1.z += bhi; h1.w += bhi;
            h2.x += bhi; h2.y += bhi; h2.z += bhi; h2.w += bhi;
            *(uint4*)(out_hi + base) = h1;
            *(uint4*)(out_hi + base + 4) = h2;
        }
    } else {
        for (int e = 0; e < 8; e++) {
            int i = base + e;
            if (i < n) { out_lo[i] += blo; if (HI) out_hi[i] += bhi; }
        }
    }
}

// ---------------- stage-1 scatter ----------------
__global__ void k_scatter(const u32* pvid, int n, const u32* starts, u32* cursor, u32* ptbuf)
{
    int i = blockIdx.x * blockDim.x + threadIdx.x;
    if (i >= n) return;
    u32 g = pvid[i];
    if (g == 0xFFFFFFFFu) return;
    u32 pos = atomicAdd(&cursor[g], 1u);
    ptbuf[starts[g] + pos] = (u32)i;
}

// ---------------- fused: per-cell sort + voxel build + roi mask ----------------
__global__ void k_cells(const u32* cnt1, const u32* starts, const u32* flagsc,
                        const u32* roibm, u32* ptbuf, u32* npm, u32* vstart)
{
    int c = blockIdx.x * blockDim.x + threadIdx.x;
    if (c >= NC1) return;
    u32 n = cnt1[c];
    if (!n) return;
    int f = c / C1, lv = c % C1;
    u32 slot = flagsc[c] - flagsc[f * C1];
    if (slot >= MAXV) return;
    int cx = lv % GX1, cy = lv / GX1;
    u32 idx = (u32)f * MAXV + slot;
    u32 s0 = starts[c];
    vstart[idx] = s0;
    u32 bit = (roibm[(size_t)f * (GY1 * RBW) + cy * RBW + (cx >> 5)] >> (cx & 31)) & 1u;
    if (!bit) return;  // npm stays 0 from init
    npm[idx] = n < 32u ? n : 32u;
    // stable order within voxel = ascending point index: insertion sort
    for (u32 a = 1; a < n; a++) {
        u32 v = ptbuf[s0 + a];
        int bp2 = (int)a;
        while (bp2 > 0 && ptbuf[s0 + bp2 - 1] > v) { ptbuf[s0 + bp2] = ptbuf[s0 + bp2 - 1]; bp2--; }
        ptbuf[s0 + bp2] = v;
    }
}

// ---------------- emit kept points, mark fine-voxel bitmap ----------------
__global__ void k_emitkept(const float* P, const u32* npm, const u32* koff, const u32* vstart,
                           const u32* ptbuf, u32* kept, u32* fvid, u32* bitmap)
{
    int idx = blockIdx.x * blockDim.x + threadIdx.x;
    if (idx >= NF * MAXV) return;
    u32 m = npm[idx];
    if (!m) return;
    u32 base = koff[idx];
    u32 vs = vstart[idx];
    u32 f = (u32)idx / MAXV;
    for (u32 r = 0; r < m; r++) {
        u32 pidx = ptbuf[vs + r];
        u32 seq = base + r;
        kept[seq] = pidx;
        const float* p = P + (size_t)pidx * 6;
        float fx = floorf((p[1] - PCX) / VSH);
        float fy = floorf((p[2] - PCY) / VSH);
        float fz = floorf((p[3] - PCZ) / VSH);
        u32 pk = 0xFFFFFFFFu;
        if (fx >= 0.f && fx < (float)GX2 && fy >= 0.f && fy < (float)GY2 &&
            fz >= 0.f && fz < (float)GZ2) {
            u32 vid = ((u32)fz * GY2 + (u32)fy) * GX2 + (u32)fx;
            pk = (f << 25) | vid;
            atomicOr(&bitmap[f * WPF + (vid >> 5)], 1u << (vid & 31));
        }
        fvid[seq] = pk;
    }
}

// ---------------- insert kept seqs into per-voxel 5-min sorted arrays ----------------
__global__ void k_insert(const u32* fvid, const u32* koffend, const u32* bitmap,
                         const u32* wordpref, u32* slotseq)
{
    u32 i = blockIdx.x * blockDim.x + threadIdx.x;
    u32 Mt = koffend[0];
    if (i >= Mt) return;
    u32 pk = fvid[i];
    if (pk == 0xFFFFFFFFu) return;
    u32 f = pk >> 25, vid = pk & 0x1FFFFFFu;
    u32 gw = f * WPF + (vid >> 5);
    u32 slot = wordpref[gw] - wordpref[f * WPF] +
               (u32)__popc(bitmap[gw] & ((1u << (vid & 31)) - 1u));
    if (slot >= (u32)MAXV) return;
    u32* arr = slotseq + (size_t)(f * MAXV + slot) * KK2;
    u32 val = i;
    #pragma unroll
    for (int j = 0; j < KK2; j++) {
        u32 old = atomicMin(&arr[j], val);
        if (old == 0xFFFFFFFFu) break;     // landed in empty slot
        val = old > val ? old : val;       // carry displaced value
    }
}

// ---------------- fill per-frame slot->vid table + row counts ----------------
__global__ void k_fillvid(const u32* bitmap, const u32* wordpref, u32* vid2, u32* rowcnt)
{
    u32 gw = blockIdx.x * blockDim.x + threadIdx.x;
    if (gw >= (u32)NF * WPF) return;
    u32 bits = bitmap[gw];
    if (!bits) return;
    u32 f = gw / WPF;
    u32 base = wordpref[gw] - wordpref[f * WPF];
    u32 vid0 = (gw - f * WPF) << 5;
    while (bits) {
        u32 bpos = (u32)__ffs(bits) - 1u;
        u32 slot = base++;
        if (slot < (u32)MAXV) {
            u32 vid = vid0 + bpos;
            vid2[f * MAXV + slot] = vid;
            atomicAdd(&rowcnt[f * NR2 + vid / GX2], 1u);
        }
        bits &= bits - 1u;
    }
}

// ---------------- per-(frame, roi) selection + output ----------------
__global__ void __launch_bounds__(256) k_output(const float* P, const u32* boxp,
    const u32* rowstart, const u32* vid2, const u32* slotseq, const u32* kept, float* out)
{
    __shared__ u32 rlo_s[MAXROWS];
    __shared__ u32 rpref_s[MAXROWS];
    __shared__ u32 ssum[256];
    __shared__ int sidx[NSAMP];
    __shared__ float feat[KK2 * NSAMP][5];
    __shared__ u32 pmf[KK2 * NSAMP];
    __shared__ int sel[NSAMP];
    __shared__ int nsel_s;
    __shared__ u32 M_s;

    int bid = blockIdx.x, tid = threadIdx.x;
    int f = bid / RR, r = bid % RR;
    int b = f / TT, t = f % TT;
    const u32* bp = boxp + bid * 12;
    float bx = __uint_as_float(bp[0]);
    float by = __uint_as_float(bp[1]);
    float cr2 = __uint_as_float(bp[2]);
    float zmax = __uint_as_float(bp[3]);
    int Q1x = (int)bp[7], Q1y = (int)bp[8], irad2 = (int)bp[9];

    u32 fb = rowstart[f * NR2];
    u32 fe = rowstart[(f + 1) * NR2];
    int nv2 = (int)(fe - fb);
    const u32* vidf = vid2 + f * MAXV;

    int cxlo = Q1x - irad2 + 1; if (cxlo < 0) cxlo = 0;
    int cxhi = Q1x + irad2 - 1; if (cxhi > GX2 - 1) cxhi = GX2 - 1;
    int cylo = Q1y - irad2 + 1; if (cylo < 0) cylo = 0;
    int cyhi = Q1y + irad2 - 1; if (cyhi > GY2 - 1) cyhi = GY2 - 1;
    int ny = cyhi - cylo + 1;
    int nrows = (cxlo <= cxhi && cylo <= cyhi && nv2 > 0) ? GZ2 * ny : 0;
    if (nrows > MAXROWS) nrows = MAXROWS;

    // phase A: per-row slot ranges via rowstart table (blocked per thread)
    u32 myrlo[RPT], myrpref[RPT];
    u32 lsum = 0;
    #pragma unroll
    for (int e = 0; e < RPT; e++) {
        int ri = tid * RPT + e;
        myrpref[e] = lsum;
        myrlo[e] = 0;
        if (ri < nrows) {
            int cz = ri / ny, cy = cylo + (ri - cz * ny);
            int gr = f * NR2 + cz * GY2 + cy;
            u32 lo = rowstart[gr] - fb, hi = rowstart[gr + 1] - fb;
            u32 vlo = ((u32)cz * GY2 + (u32)cy) * GX2 + (u32)cxlo;
            u32 vhi = vlo + (u32)(cxhi - cxlo);
            u32 s0 = lo, e0 = hi;
            while (s0 < e0) { u32 m = (s0 + e0) >> 1; if (vidf[m] < vlo) s0 = m + 1; else e0 = m; }
            u32 s1 = s0, e1 = hi;
            while (s1 < e1) { u32 m = (s1 + e1) >> 1; if (vidf[m] <= vhi) s1 = m + 1; else e1 = m; }
            myrlo[e] = s0;
            lsum += s1 - s0;
        }
    }
    ssum[tid] = lsum;
    __syncthreads();
    for (int off = 1; off < 256; off <<= 1) {
        u32 y = (tid >= off) ? ssum[tid - off] : 0;
        __syncthreads();
        ssum[tid] += y;
        __syncthreads();
    }
    u32 texcl = ssum[tid] - lsum;
    if (tid == 255) M_s = ssum[255];
    #pragma unroll
    for (int e = 0; e < RPT; e++) {
        int ri = tid * RPT + e;
        rlo_s[ri] = myrlo[e];
        rpref_s[ri] = texcl + myrpref[e];
    }
    __syncthreads();

    u32 M = M_s;
    int nt = (int)(M < (u32)NSAMP ? M : (u32)NSAMP);
    // phase B1: matched slots in ascending order (rows ascending => slots ascending)
    if (tid < nt) {
        int lo = 0, hi = nrows - 1;
        while (lo < hi) { int m = (lo + hi + 1) >> 1; if (rpref_s[m] <= (u32)tid) lo = m; else hi = m - 1; }
        sidx[tid] = (int)(rlo_s[lo] + ((u32)tid - rpref_s[lo]));
    }
    __syncthreads();
    // phase B2: top_k false-fill with lowest non-matching slot indices
    if (tid == 0) {
        int c = nt, p = 0, s = 0;
        while (c < NSAMP) {
            if (p < nt && sidx[p] == s) { p++; s++; continue; }
            sidx[c++] = s++;
        }
    }
    __syncthreads();

    // phase C: gather sv in flat (k2-major) order, evaluate pm
    for (int j = tid; j < KK2 * NSAMP; j += 256) {
        int k2 = j >> 5, s = j & 31;
        int slot = sidx[s];
        float px = 0.f, py = 0.f, pz = 0.f, pi = 0.f, pt = 0.f;
        if (slot < nv2) {
            u32 seq = slotseq[(size_t)(f * MAXV + slot) * KK2 + k2];
            if (seq != 0xFFFFFFFFu) {
                u32 pidx = kept[seq];
                const float* p = P + (size_t)pidx * 6;
                px = p[1]; py = p[2]; pz = p[3]; pi = p[4]; pt = p[5];
            }
        }
        feat[j][0] = px; feat[j][1] = py; feat[j][2] = pz; feat[j][3] = pi; feat[j][4] = pt;
        float ex = px - bx, ey = py - by;
        pmf[j] = (ex * ex + ey * ey < cr2 && pz <= zmax) ? 1u : 0u;
    }
    __syncthreads();

    // phase D: top_k over pm in flat order
    if (tid == 0) {
        int c = 0;
        for (int j = 0; j < KK2 * NSAMP && c < NSAMP; j++)
            if (pmf[j]) sel[c++] = j;
        nsel_s = c;
    }
    __syncthreads();

    // phase E: write 32 rows x 5 feats
    int obase = ((b * RR + r) * (TT * NSAMP) + t * NSAMP) * 5;
    for (int w = tid; w < NSAMP * 5; w += 256) {
        int row = w / 5, col = w % 5;
        float v = (row < nsel_s) ? feat[sel[row]][col] : 0.f;
        out[obase + w] = v;
    }
}

extern "C" void kernel_launch(void* const* d_in, const int* in_sizes, int n_in,
                              void* d_out, int out_size, void* d_ws, size_t ws_size,
                              hipStream_t stream)
{
    const float* P = (const float*)d_in[0];
    const float* traj = (const float*)d_in[1];
    const float* back = (const float*)d_in[2];
    const unsigned char* vlb = (const unsigned char*)d_in[3];
    float* out = (float*)d_out;
    int N = in_sizes[0] / 6;
    if (N > NMAXP) N = NMAXP;

    char* cur = (char*)d_ws;
    auto carve = [&](size_t bytes) -> char* {
        char* p = cur;
        cur += (bytes + 255) & ~(size_t)255;
        return p;
    };

    // ---- zero zone 1: cnt1 + cursor (contiguous) ----
    char* zoneZ1 = cur;
    u32* cnt1   = (u32*)carve((size_t)NC1 * 4);
    u32* cursor = (u32*)carve((size_t)NC1 * 4);
    size_t z1_bytes = (size_t)(cur - zoneZ1);
    // ---- scan outputs (no init needed; fully written) ----
    u32* flagsc = (u32*)carve((size_t)(NC1 + 1) * 4);
    u32* starts = (u32*)carve((size_t)(NC1 + 1) * 4);
    // wordpref aliases [cnt1, cursor, flagsc, starts] (18.1MB >= 17MB), all dead before scan(3)
    u32* wordpref = (u32*)zoneZ1;
    // ---- zero zone 2: npm + rowcnt + roibm + bitmap (contiguous) ----
    char* zoneZ2 = cur;
    u32* npm    = (u32*)carve((size_t)NF * MAXV * 4);
    u32* rowcnt = (u32*)carve((size_t)NF * NR2 * 4);
    u32* roibm  = (u32*)carve((size_t)NF * GY1 * RBW * 4);
    u32* bitmap = (u32*)carve((size_t)NF * WPF * 4);
    size_t z2_bytes = (size_t)(cur - zoneZ2);
    // ---- 0xFF zone: slotseq ----
    u32* slotseq = (u32*)carve((size_t)NF * MAXV * KK2 * 4);
    size_t ff_bytes = (size_t)((char*)cur - (char*)slotseq);

    u64* partials = (u64*)carve(4096 * 8);
    u32* pvid     = (u32*)carve((size_t)NMAXP * 4);
    u32* ptbuf    = (u32*)carve((size_t)NMAXP * 4);
    u32* vstart   = (u32*)carve((size_t)NF * MAXV * 4);
    u32* koff     = (u32*)carve((size_t)(NF * MAXV + 1) * 4);
    u32* boxp     = (u32*)carve((size_t)NF * RR * 12 * 4);
    u32* kept     = (u32*)carve((size_t)NMAXP * 4);
    u32* fvid     = (u32*)carve((size_t)NMAXP * 4);
    u32* vid2     = (u32*)carve((size_t)NF * MAXV * 4);
    u32* rowstart = (u32*)carve((size_t)(NF * NR2 + 1) * 4);
    if ((size_t)(cur - (char*)d_ws) > ws_size) return;  // insufficient workspace

    // custom init (rocclr fillBuffer was ~40us for 8MB; this is one BW-bound kernel)
    k_init<<<1024, 256, 0, stream>>>((u32*)zoneZ1, (u32)(z1_bytes / 16),
                                     (u32*)zoneZ2, (u32)(z2_bytes / 16),
                                     slotseq, (u32)(ff_bytes / 16));

    auto scan = [&](int mode, const u32* in, u32* lo, u32* hi, int n) {
        int nb = (n + 2047) / 2048;
        if (mode == 0)      k_scan_partial<0><<<nb, 256, 0, stream>>>(in, lo, hi, partials, n);
        else if (mode == 1) k_scan_partial<1><<<nb, 256, 0, stream>>>(in, lo, hi, partials, n);
        else                k_scan_partial<3><<<nb, 256, 0, stream>>>(in, lo, hi, partials, n);
        k_scan_level2<<<1, 256, 0, stream>>>(partials, nb, lo, hi, n);
        if (mode == 0) k_scan_addback<true><<<nb, 256, 0, stream>>>(lo, hi, partials, n);
        else           k_scan_addback<false><<<nb, 256, 0, stream>>>(lo, nullptr, partials, n);
    };

    k_roisraster<<<(NF * RR + 255) / 256, 256, 0, stream>>>(traj, back, vlb, boxp, roibm);
    k_points<<<(N + 255) / 256, 256, 0, stream>>>(P, N, pvid, cnt1);

    scan(0, cnt1, starts, flagsc, NC1);

    k_scatter<<<(N + 255) / 256, 256, 0, stream>>>(pvid, N, starts, cursor, ptbuf);
    k_cells<<<(NC1 + 255) / 256, 256, 0, stream>>>(cnt1, starts, flagsc, roibm, ptbuf, npm, vstart);

    scan(1, npm, koff, nullptr, NF * MAXV);

    k_emitkept<<<(NF * MAXV + 255) / 256, 256, 0, stream>>>(P, npm, koff, vstart, ptbuf, kept, fvid, bitmap);

    scan(3, bitmap, wordpref, nullptr, NF * WPF);

    k_insert<<<NPAD / 256, 256, 0, stream>>>(fvid, koff + NF * MAXV, bitmap, wordpref, slotseq);
    k_fillvid<<<((u32)NF * WPF + 255) / 256, 256, 0, stream>>>(bitmap, wordpref, vid2, rowcnt);

    scan(1, rowcnt, rowstart, nullptr, NF * NR2);

    k_output<<<NF * RR, 256, 0, stream>>>(P, boxp, rowstart, vid2, slotseq, kept, out);
}